// Round 6
// baseline (213.277 us; speedup 1.0000x reference)
//
#include <hip/hip_runtime.h>

#define HH 128
#define WW 256
#define CH 64
#define HWP (HH * WW)   // 32768

typedef __attribute__((ext_vector_type(8))) __bf16 bf16x8;
typedef __attribute__((ext_vector_type(16))) float float16;

__device__ __forceinline__ unsigned short f2bf(float f) {
    unsigned u = __float_as_uint(f);
    u += 0x7fffu + ((u >> 16) & 1u);     // RNE
    return (unsigned short)(u >> 16);
}
__device__ __forceinline__ float bf2f(unsigned short u) {
    return __uint_as_float((unsigned)u << 16);
}

// ---------------------------------------------------------------------------
// Weight prep -> bf16 B-fragment layouts for mfma_f32_32x32x16_bf16.
// frag[((kc*NT + nt)*64 + lane)*8 + j] = W[n][k], n = nt*32+(lane&31),
// k = kc*16 + (lane>>5)*8 + j.
// Segments: [0)rb_w1 [36864)rb_w2 [73728)b1 [77824)b2||b3 [86016)fus [94208)
// ---------------------------------------------------------------------------
__global__ __launch_bounds__(256) void prep_w_k(
    const float* __restrict__ w1, const float* __restrict__ w2,
    const float* __restrict__ b1w, const float* __restrict__ b2w,
    const float* __restrict__ b3w, const float* __restrict__ fusw,
    unsigned short* __restrict__ wB)
{
    int e = blockIdx.x * 256 + threadIdx.x;
    if (e >= 94208) return;
    float val;
    if (e < 73728) {
        const float* w = (e < 36864) ? w1 : w2;
        int t = (e < 36864) ? e : e - 36864;
        int j = t & 7, L = (t >> 3) & 63, nb = (t >> 9) & 1, kc = t >> 10;
        int k  = kc * 16 + (L >> 5) * 8 + j;
        int n  = nb * 32 + (L & 31);
        int kd = k >> 6, ci = k & 63;
        val = w[(n * 64 + ci) * 9 + kd];
    } else {
        int t = e - 73728;
        if (t < 4096) {                       // Q: K=64, NT=2
            int j = t & 7, L = (t >> 3) & 63, i3 = t >> 9;
            int nt = i3 & 1, kc = i3 >> 1;
            int n = nt * 32 + (L & 31), k = kc * 16 + (L >> 5) * 8 + j;
            val = b1w[n * 64 + k];
        } else if (t < 12288) {               // S||R: K=64, NT=4
            t -= 4096;
            int j = t & 7, L = (t >> 3) & 63, i3 = t >> 9;
            int nt = i3 & 3, kc = i3 >> 2;
            int n = nt * 32 + (L & 31), k = kc * 16 + (L >> 5) * 8 + j;
            val = (n < 64) ? b2w[n * 64 + k] : b3w[(n - 64) * 64 + k];
        } else {                              // FUS: K=128, NT=2
            t -= 12288;
            int j = t & 7, L = (t >> 3) & 63, i3 = t >> 9;
            int nt = i3 & 1, kc = i3 >> 1;
            int n = nt * 32 + (L & 31), k = kc * 16 + (L >> 5) * 8 + j;
            val = fusw[n * 128 + k];
        }
    }
    wB[e] = f2bf(val);
}

// ---------------------------------------------------------------------------
// NCHW f32 -> T-layout bf16 (p-major rows of 64 ch).  2048 blocks x 256.
// ---------------------------------------------------------------------------
__global__ __launch_bounds__(256) void toT_k(
    const float* __restrict__ xl, const float* __restrict__ xr,
    unsigned short* __restrict__ XT)
{
    __shared__ __align__(16) unsigned short sT[64 * 68];
    const int tid = threadIdx.x;
    const int side = blockIdx.x >> 10;
    const int i0   = blockIdx.x & 1023;
    const int gp0  = i0 * 64;
    const int b    = gp0 >> 15;
    const int pofs = gp0 & (HWP - 1);
    const float* in = (side ? xr : xl) + (size_t)b * CH * HWP + pofs;

    for (int i = tid; i < 4096; i += 256) {
        int ci = i >> 6, px = i & 63;
        sT[px * 68 + ci] = f2bf(in[(size_t)ci * HWP + px]);
    }
    __syncthreads();
    const int px = tid >> 2, q = tid & 3;
    unsigned short* op = XT + ((size_t)(side * 2 + b) * HWP + pofs + px) * 64;
#pragma unroll
    for (int r = 0; r < 2; ++r)
        *(uint4*)&op[(q * 2 + r) * 8] = *(uint4*)&sT[px * 68 + (q * 2 + r) * 8];
}

// halo staging for 128-px strips: 3 rows x 130 cols, 3120 16B tasks / 256 thr
__device__ __forceinline__ void stage_halo130(
    unsigned short* sA, const unsigned short* inT, int x0, int y, int tid)
{
    for (int i = tid; i < 3120; i += 256) {
        int cell = i >> 3, j = i & 7;
        int row = cell / 130, col = cell - row * 130;
        int gy = y + row - 1, gx = x0 + col - 1;
        uint4 v = make_uint4(0, 0, 0, 0);
        if ((unsigned)gy < HH && (unsigned)gx < WW)
            v = *(const uint4*)&inT[(size_t)(gy * WW + gx) * 64 + j * 8];
        *(uint4*)&sA[(row * 130 + col) * 68 + j * 8] = v;
    }
}

// ---------------------------------------------------------------------------
// conv1: T bf16 in -> lrelu -> T bf16 out.  grid (2,128,4): z = side*2+b.
// Block: 128 px x 64 co, 4 waves; wave = 64 px (2 M-tiles) x 32 co.
// Each B-fragment load feeds 2 MFMAs.
// ---------------------------------------------------------------------------
__global__ __launch_bounds__(256) void conv1_k(
    const unsigned short* __restrict__ XT, const unsigned short* __restrict__ wB,
    unsigned short* __restrict__ H1T)
{
    __shared__ __align__(16) unsigned short sA[3 * 130 * 68];   // 53040 B

    const int tid = threadIdx.x;
    const int x0  = blockIdx.x * 128;
    const int y   = blockIdx.y;
    const int sb  = blockIdx.z;
    const unsigned short* inT = XT + (size_t)sb * HWP * 64;

    stage_halo130(sA, inT, x0, y, tid);
    __syncthreads();

    const int lane = tid & 63, wv = tid >> 6;
    const int h = wv & 1, nw = wv >> 1;
    const int m = lane & 31, kg = lane >> 5;

    float16 acc0, acc1;
#pragma unroll
    for (int i = 0; i < 16; ++i) { acc0[i] = 0.f; acc1[i] = 0.f; }

#pragma unroll
    for (int kc = 0; kc < 36; ++kc) {
        const int kd = kc >> 2, hh = kc & 3;
        const int dy = kd / 3, dx = kd - dy * 3;
        bf16x8 bfg = *(const bf16x8*)&wB[((kc * 2 + nw) * 64 + lane) * 8];
        const int base = (dy * 130 + h * 64 + m + dx) * 68 + hh * 16 + kg * 8;
        bf16x8 af0 = *(const bf16x8*)&sA[base];
        bf16x8 af1 = *(const bf16x8*)&sA[base + 32 * 68];
        acc0 = __builtin_amdgcn_mfma_f32_32x32x16_bf16(af0, bfg, acc0, 0, 0, 0);
        acc1 = __builtin_amdgcn_mfma_f32_32x32x16_bf16(af1, bfg, acc1, 0, 0, 0);
    }

    __syncthreads();
    unsigned short* sCb = sA;                 // [px][ci] stride 68, 128 px
    const int n = nw * 32 + (lane & 31);
#pragma unroll
    for (int r = 0; r < 16; ++r) {
        int pr = h * 64 + (r & 3) + 8 * (r >> 2) + 4 * kg;
        float v0 = acc0[r]; v0 = v0 > 0.f ? v0 : 0.1f * v0;
        float v1 = acc1[r]; v1 = v1 > 0.f ? v1 : 0.1f * v1;
        sCb[pr * 68 + n] = f2bf(v0);
        sCb[(pr + 32) * 68 + n] = f2bf(v1);
    }
    __syncthreads();

    const int px = tid >> 1, q = tid & 1;
    unsigned short* op = H1T + ((size_t)sb * HWP + y * WW + x0 + px) * 64 + q * 32;
#pragma unroll
    for (int j = 0; j < 4; ++j)
        *(uint4*)&op[j * 8] = *(uint4*)&sCb[px * 68 + q * 32 + j * 8];
}

// ---------------------------------------------------------------------------
// conv2 + residual + fused 1x1 projections.  Same 128-px block structure.
// side 0 (left):  buf tile -> Q proj -> QT bf16.
// side 1 (right): buf tile -> S,R proj -> ST, RT bf16.
// ---------------------------------------------------------------------------
__global__ __launch_bounds__(256) void conv2_k(
    const unsigned short* __restrict__ H1T, const unsigned short* __restrict__ XT,
    const unsigned short* __restrict__ wB2, const unsigned short* __restrict__ wQ,
    const unsigned short* __restrict__ wSR, const float* __restrict__ b1b,
    const float* __restrict__ b2b, const float* __restrict__ b3b,
    unsigned short* __restrict__ QT, unsigned short* __restrict__ ST,
    unsigned short* __restrict__ RT)
{
    __shared__ __align__(16) unsigned short sA[3 * 130 * 68];   // 53040 B

    const int tid = threadIdx.x;
    const int x0  = blockIdx.x * 128;
    const int y   = blockIdx.y;
    const int sb  = blockIdx.z;
    const int side = sb >> 1, b = sb & 1;
    const unsigned short* inT = H1T + (size_t)sb * HWP * 64;

    stage_halo130(sA, inT, x0, y, tid);
    __syncthreads();

    const int lane = tid & 63, wv = tid >> 6;
    const int h = wv & 1, nw = wv >> 1;
    const int m = lane & 31, kg = lane >> 5;

    float16 acc0, acc1;
#pragma unroll
    for (int i = 0; i < 16; ++i) { acc0[i] = 0.f; acc1[i] = 0.f; }

#pragma unroll
    for (int kc = 0; kc < 36; ++kc) {
        const int kd = kc >> 2, hh = kc & 3;
        const int dy = kd / 3, dx = kd - dy * 3;
        bf16x8 bfg = *(const bf16x8*)&wB2[((kc * 2 + nw) * 64 + lane) * 8];
        const int base = (dy * 130 + h * 64 + m + dx) * 68 + hh * 16 + kg * 8;
        bf16x8 af0 = *(const bf16x8*)&sA[base];
        bf16x8 af1 = *(const bf16x8*)&sA[base + 32 * 68];
        acc0 = __builtin_amdgcn_mfma_f32_32x32x16_bf16(af0, bfg, acc0, 0, 0, 0);
        acc1 = __builtin_amdgcn_mfma_f32_32x32x16_bf16(af1, bfg, acc1, 0, 0, 0);
    }

    // residual add (bf16 x from XT) -> buf tile bf16 in sCb [px][ci]
    __syncthreads();
    unsigned short* sCb = sA;                          // halves [0, 8704)
    unsigned short* sC2 = sA + 8704;                   // proj output staging
    const int n = nw * 32 + (lane & 31);
    const unsigned short* xres = XT + ((size_t)sb * HWP + y * WW + x0) * 64;
#pragma unroll
    for (int r = 0; r < 16; ++r) {
        int pr = h * 64 + (r & 3) + 8 * (r >> 2) + 4 * kg;
        float xv0 = bf2f(xres[(size_t)pr * 64 + n]);
        float xv1 = bf2f(xres[(size_t)(pr + 32) * 64 + n]);
        sCb[pr * 68 + n] = f2bf(acc0[r] + xv0);
        sCb[(pr + 32) * 68 + n] = f2bf(acc1[r] + xv1);
    }
    __syncthreads();

    // fused projection MFMAs (K=64)
    if (side == 0) {
        float16 a0, a1;
#pragma unroll
        for (int i = 0; i < 16; ++i) { a0[i] = 0.f; a1[i] = 0.f; }
#pragma unroll
        for (int kc = 0; kc < 4; ++kc) {
            bf16x8 bfg = *(const bf16x8*)&wQ[((kc * 2 + nw) * 64 + lane) * 8];
            bf16x8 af0 = *(const bf16x8*)&sCb[(h * 64 + m) * 68 + kc * 16 + kg * 8];
            bf16x8 af1 = *(const bf16x8*)&sCb[(h * 64 + 32 + m) * 68 + kc * 16 + kg * 8];
            a0 = __builtin_amdgcn_mfma_f32_32x32x16_bf16(af0, bfg, a0, 0, 0, 0);
            a1 = __builtin_amdgcn_mfma_f32_32x32x16_bf16(af1, bfg, a1, 0, 0, 0);
        }
        float bv = b1b[n];
#pragma unroll
        for (int r = 0; r < 16; ++r) {
            int pr = h * 64 + (r & 3) + 8 * (r >> 2) + 4 * kg;
            sC2[pr * 68 + n] = f2bf(a0[r] + bv);
            sC2[(pr + 32) * 68 + n] = f2bf(a1[r] + bv);
        }
        __syncthreads();
        const int px = tid >> 1, q = tid & 1;
        unsigned short* op = QT + ((size_t)b * HWP + y * WW + x0 + px) * 64 + q * 32;
#pragma unroll
        for (int j = 0; j < 4; ++j)
            *(uint4*)&op[j * 8] = *(uint4*)&sC2[px * 68 + q * 32 + j * 8];
    } else {
        float16 a0[2], a1[2];
#pragma unroll
        for (int t = 0; t < 2; ++t)
#pragma unroll
            for (int i = 0; i < 16; ++i) { a0[t][i] = 0.f; a1[t][i] = 0.f; }
#pragma unroll
        for (int kc = 0; kc < 4; ++kc) {
            bf16x8 af0 = *(const bf16x8*)&sCb[(h * 64 + m) * 68 + kc * 16 + kg * 8];
            bf16x8 af1 = *(const bf16x8*)&sCb[(h * 64 + 32 + m) * 68 + kc * 16 + kg * 8];
#pragma unroll
            for (int t = 0; t < 2; ++t) {
                int nt = nw * 2 + t;
                bf16x8 bfg = *(const bf16x8*)&wSR[((kc * 4 + nt) * 64 + lane) * 8];
                a0[t] = __builtin_amdgcn_mfma_f32_32x32x16_bf16(af0, bfg, a0[t], 0, 0, 0);
                a1[t] = __builtin_amdgcn_mfma_f32_32x32x16_bf16(af1, bfg, a1[t], 0, 0, 0);
            }
        }
#pragma unroll
        for (int t = 0; t < 2; ++t) {
            int nn = (nw * 2 + t) * 32 + (lane & 31);
            float bv = (nn < 64) ? b2b[nn] : b3b[nn - 64];
#pragma unroll
            for (int r = 0; r < 16; ++r) {
                int pr = h * 64 + (r & 3) + 8 * (r >> 2) + 4 * kg;
                sC2[pr * 132 + nn] = f2bf(a0[t][r] + bv);
                sC2[(pr + 32) * 132 + nn] = f2bf(a1[t][r] + bv);
            }
        }
        __syncthreads();
        const int px = tid >> 1, q = tid & 1;
        const size_t prow = (size_t)b * HWP + y * WW + x0 + px;
        unsigned short* op = (q ? RT : ST) + prow * 64;
#pragma unroll
        for (int j = 0; j < 8; ++j)
            *(uint4*)&op[j * 8] = *(uint4*)&sC2[px * 132 + q * 64 + j * 8];
    }
}

// ---------------------------------------------------------------------------
// Attention: one wave per pixel.  Score phase lane=(cq,k); softmax over
// lane bits 0-3; V phase lane=channel with readlane broadcast.
// ---------------------------------------------------------------------------
__global__ __launch_bounds__(256) void attn_k(
    const unsigned short* __restrict__ QT, const unsigned short* __restrict__ ST,
    const unsigned short* __restrict__ RT, const int* __restrict__ xxs,
    const int* __restrict__ yys, unsigned short* __restrict__ bufT,
    float* __restrict__ Mout)
{
    const int tid  = threadIdx.x;
    const int lane = tid & 63;
    const size_t gp = (size_t)blockIdx.x * 4 + (tid >> 6);
    const size_t bbase = (gp >> 15) << 15;
    const int k  = lane & 15, cq = lane >> 4;

    const int flat = xxs[gp * 16 + k] * WW + yys[gp * 16 + k];

    const unsigned short* srow = ST + (bbase + (size_t)flat) * 64 + cq * 16;
    const unsigned short* qrow = QT + gp * 64 + cq * 16;
    float s = 0.f;
#pragma unroll
    for (int hh = 0; hh < 2; ++hh) {
        uint4 sv = *(const uint4*)(srow + hh * 8);
        uint4 qv = *(const uint4*)(qrow + hh * 8);
        const unsigned* sa = (const unsigned*)&sv;
        const unsigned* qa = (const unsigned*)&qv;
#pragma unroll
        for (int d = 0; d < 4; ++d) {
            s = fmaf(__uint_as_float(sa[d] << 16),
                     __uint_as_float(qa[d] << 16), s);
            s = fmaf(__uint_as_float(sa[d] & 0xffff0000u),
                     __uint_as_float(qa[d] & 0xffff0000u), s);
        }
    }
    s += __shfl_xor(s, 16, 64);
    s += __shfl_xor(s, 32, 64);            // full score[k] on all lanes

    float mx = s;
#pragma unroll
    for (int mm = 1; mm <= 8; mm <<= 1) mx = fmaxf(mx, __shfl_xor(mx, mm, 64));
    const float e = __expf(s - mx);
    float sum = e;
#pragma unroll
    for (int mm = 1; mm <= 8; mm <<= 1) sum += __shfl_xor(sum, mm, 64);
    const float mval = e * (1.f / sum);

    if (lane < 16) Mout[gp * 16 + lane] = mval;

    const unsigned short* rbase = RT + bbase * 64;
    float acc = 0.f;
#pragma unroll
    for (int kk = 0; kk < 16; ++kk) {
        int   fi = __builtin_amdgcn_readlane(flat, kk);
        float mk = __uint_as_float(
            __builtin_amdgcn_readlane(__float_as_uint(mval), kk));
        acc = fmaf(mk, bf2f(rbase[(size_t)fi * 64 + lane]), acc);
    }
    bufT[gp * 64 + lane] = f2bf(acc);
}

// ---------------------------------------------------------------------------
// Fusion 1x1 via MFMA: K=128 (bufT rows + xlT rows, all bf16), NCHW f32 out.
// ---------------------------------------------------------------------------
__global__ __launch_bounds__(256) void fuse_k(
    const unsigned short* __restrict__ bufT, const unsigned short* __restrict__ XT,
    const unsigned short* __restrict__ wfrag, const float* __restrict__ bias,
    float* __restrict__ out)
{
    __shared__ __align__(16) unsigned char smem[64 * 68 * 4];  // 17408 B
    unsigned short* sA = (unsigned short*)smem;   // [px][k] stride 132 halves
    float* sC = (float*)smem;                     // [co][px] stride 68 dwords

    const int tid = threadIdx.x;
    const size_t gp0 = (size_t)blockIdx.x * 64;
    const int b    = (int)(gp0 >> 15);
    const int pofs = (int)(gp0 & (HWP - 1));
    const unsigned short* xlT = XT + ((size_t)b * HWP + pofs) * 64;  // side 0

    for (int i = tid; i < 1024; i += 256) {
        int px = i >> 4, j = i & 15;
        uint4 v;
        if (j < 8) v = *(const uint4*)&bufT[(gp0 + px) * 64 + j * 8];
        else       v = *(const uint4*)&xlT[(size_t)px * 64 + (j - 8) * 8];
        *(uint4*)&sA[px * 132 + ((j < 8) ? j * 8 : 64 + (j - 8) * 8)] = v;
    }
    __syncthreads();

    const int lane = tid & 63, wv = tid >> 6;
    const int mw = wv & 1, nw = wv >> 1;
    const int m = lane & 31, kg = lane >> 5;
    const int px_l = mw * 32 + m;

    float16 acc;
#pragma unroll
    for (int i = 0; i < 16; ++i) acc[i] = 0.f;

#pragma unroll
    for (int kc = 0; kc < 8; ++kc) {
        bf16x8 af = *(const bf16x8*)&sA[px_l * 132 + kc * 16 + kg * 8];
        bf16x8 bf = *(const bf16x8*)&wfrag[((kc * 2 + nw) * 64 + lane) * 8];
        acc = __builtin_amdgcn_mfma_f32_32x32x16_bf16(af, bf, acc, 0, 0, 0);
    }
    __syncthreads();

    const int co_l = nw * 32 + (lane & 31);
#pragma unroll
    for (int r = 0; r < 16; ++r) {
        int pr = mw * 32 + (r & 3) + 8 * (r >> 2) + 4 * kg;
        sC[co_l * 68 + pr] = acc[r];
    }
    __syncthreads();

    const int co = tid >> 2, p0 = (tid & 3) * 16;
    const float bv = bias[co];
    float* op = out + ((size_t)b * CH + co) * HWP + pofs + p0;
#pragma unroll
    for (int q = 0; q < 4; ++q) {
        float4 v = *(float4*)&sC[co * 68 + p0 + q * 4];
        v.x += bv; v.y += bv; v.z += bv; v.w += bv;
        *(float4*)&op[q * 4] = v;
    }
}

// ---------------------------------------------------------------------------
extern "C" void kernel_launch(void* const* d_in, const int* in_sizes, int n_in,
                              void* d_out, int out_size, void* d_ws, size_t ws_size,
                              hipStream_t stream)
{
    const float* x_left  = (const float*)d_in[0];
    const float* x_right = (const float*)d_in[1];
    const int*   xxs     = (const int*)d_in[2];
    const int*   yys     = (const int*)d_in[3];
    const float* rb_w1   = (const float*)d_in[5];
    const float* rb_w2   = (const float*)d_in[6];
    const float* b1_w    = (const float*)d_in[7];
    const float* b1_b    = (const float*)d_in[8];
    const float* b2_w    = (const float*)d_in[9];
    const float* b2_b    = (const float*)d_in[10];
    const float* b3_w    = (const float*)d_in[11];
    const float* b3_b    = (const float*)d_in[12];
    const float* fus_w   = (const float*)d_in[13];
    const float* fus_b   = (const float*)d_in[14];

    float* out  = (float*)d_out;                 // (2,64,128,256)
    float* Mout = out + (size_t)2 * CH * HWP;    // (2,32768,1,16)

    unsigned short* ws2 = (unsigned short*)d_ws;
    unsigned short* XT   = ws2;                  // [side][b][HWP][64]  8388608
    unsigned short* H1T  = ws2 + 8388608;
    unsigned short* QT   = ws2 + 16777216;       // [b][HWP][64]        4194304
    unsigned short* ST   = ws2 + 20971520;
    unsigned short* RT   = ws2 + 25165824;
    unsigned short* bufT = ws2 + 29360128;
    unsigned short* wB   = ws2 + 33554432;       // 94208 halves

    prep_w_k<<<368, 256, 0, stream>>>(rb_w1, rb_w2, b1_w, b2_w, b3_w, fus_w, wB);
    toT_k<<<2048, 256, 0, stream>>>(x_left, x_right, XT);

    dim3 cgrid(WW / 128, HH, 4), cblk(256);
    conv1_k<<<cgrid, cblk, 0, stream>>>(XT, wB, H1T);
    conv2_k<<<cgrid, cblk, 0, stream>>>(H1T, XT, wB + 36864, wB + 73728,
                                        wB + 77824, b1_b, b2_b, b3_b, QT, ST, RT);

    attn_k<<<16384, 256, 0, stream>>>(QT, ST, RT, xxs, yys, bufT, Mout);
    fuse_k<<<1024, 256, 0, stream>>>(bufT, XT, wB + 86016, fus_b, out);
}

// Round 7
// 196.201 us; speedup vs baseline: 1.0870x; 1.0870x over previous
//
#include <hip/hip_runtime.h>

#define HH 128
#define WW 256
#define CH 64
#define HWP (HH * WW)   // 32768

typedef __attribute__((ext_vector_type(8))) __bf16 bf16x8;
typedef __attribute__((ext_vector_type(16))) float float16;

__device__ __forceinline__ unsigned short f2bf(float f) {
    unsigned u = __float_as_uint(f);
    u += 0x7fffu + ((u >> 16) & 1u);     // RNE
    return (unsigned short)(u >> 16);
}
__device__ __forceinline__ float bf2f(unsigned short u) {
    return __uint_as_float((unsigned)u << 16);
}

// ---------------------------------------------------------------------------
// Weight prep -> bf16 B-fragment layouts for mfma_f32_32x32x16_bf16.
// frag[((kc*NT + nt)*64 + lane)*8 + j] = W[n][k], n = nt*32+(lane&31),
// k = kc*16 + (lane>>5)*8 + j.
// Segments: [0)rb_w1 [36864)rb_w2 [73728)b1 [77824)b2||b3 [86016)fus [94208)
// ---------------------------------------------------------------------------
__global__ __launch_bounds__(256) void prep_w_k(
    const float* __restrict__ w1, const float* __restrict__ w2,
    const float* __restrict__ b1w, const float* __restrict__ b2w,
    const float* __restrict__ b3w, const float* __restrict__ fusw,
    unsigned short* __restrict__ wB)
{
    int e = blockIdx.x * 256 + threadIdx.x;
    if (e >= 94208) return;
    float val;
    if (e < 73728) {
        const float* w = (e < 36864) ? w1 : w2;
        int t = (e < 36864) ? e : e - 36864;
        int j = t & 7, L = (t >> 3) & 63, nb = (t >> 9) & 1, kc = t >> 10;
        int k  = kc * 16 + (L >> 5) * 8 + j;
        int n  = nb * 32 + (L & 31);
        int kd = k >> 6, ci = k & 63;
        val = w[(n * 64 + ci) * 9 + kd];
    } else {
        int t = e - 73728;
        if (t < 4096) {                       // Q: K=64, NT=2
            int j = t & 7, L = (t >> 3) & 63, i3 = t >> 9;
            int nt = i3 & 1, kc = i3 >> 1;
            int n = nt * 32 + (L & 31), k = kc * 16 + (L >> 5) * 8 + j;
            val = b1w[n * 64 + k];
        } else if (t < 12288) {               // S||R: K=64, NT=4
            t -= 4096;
            int j = t & 7, L = (t >> 3) & 63, i3 = t >> 9;
            int nt = i3 & 3, kc = i3 >> 2;
            int n = nt * 32 + (L & 31), k = kc * 16 + (L >> 5) * 8 + j;
            val = (n < 64) ? b2w[n * 64 + k] : b3w[(n - 64) * 64 + k];
        } else {                              // FUS: K=128, NT=2
            t -= 12288;
            int j = t & 7, L = (t >> 3) & 63, i3 = t >> 9;
            int nt = i3 & 1, kc = i3 >> 1;
            int n = nt * 32 + (L & 31), k = kc * 16 + (L >> 5) * 8 + j;
            val = fusw[n * 128 + k];
        }
    }
    wB[e] = f2bf(val);
}

// ---------------------------------------------------------------------------
// NCHW f32 -> T-layout bf16 (p-major rows of 64 ch).  2048 blocks x 256.
// ---------------------------------------------------------------------------
__global__ __launch_bounds__(256) void toT_k(
    const float* __restrict__ xl, const float* __restrict__ xr,
    unsigned short* __restrict__ XT)
{
    __shared__ __align__(16) unsigned short sT[64 * 68];
    const int tid = threadIdx.x;
    const int side = blockIdx.x >> 10;
    const int i0   = blockIdx.x & 1023;
    const int gp0  = i0 * 64;
    const int b    = gp0 >> 15;
    const int pofs = gp0 & (HWP - 1);
    const float* in = (side ? xr : xl) + (size_t)b * CH * HWP + pofs;

    for (int i = tid; i < 4096; i += 256) {
        int ci = i >> 6, px = i & 63;
        sT[px * 68 + ci] = f2bf(in[(size_t)ci * HWP + px]);
    }
    __syncthreads();
    const int px = tid >> 2, q = tid & 3;
    unsigned short* op = XT + ((size_t)(side * 2 + b) * HWP + pofs + px) * 64;
#pragma unroll
    for (int r = 0; r < 2; ++r)
        *(uint4*)&op[(q * 2 + r) * 8] = *(uint4*)&sT[px * 68 + (q * 2 + r) * 8];
}

// halo staging: 3 rows x 66 cols, 1584 coalesced 16B tasks over 256 thr
__device__ __forceinline__ void stage_halo(
    unsigned short* sA, const unsigned short* inT, int x0, int y, int tid)
{
    for (int i = tid; i < 1584; i += 256) {
        int cell = i >> 3, j = i & 7;
        int row = cell / 66, col = cell - row * 66;
        int gy = y + row - 1, gx = x0 + col - 1;
        uint4 v = make_uint4(0, 0, 0, 0);
        if ((unsigned)gy < HH && (unsigned)gx < WW)
            v = *(const uint4*)&inT[(size_t)(gy * WW + gx) * 64 + j * 8];
        *(uint4*)&sA[(row * 66 + col) * 68 + j * 8] = v;
    }
}

// ---------------------------------------------------------------------------
// conv1: T bf16 in -> lrelu -> T bf16 out.  grid (4,128,4): z = side*2+b.
// (round-5 structure: 64 px x 64 co, 27KB LDS, ~6 blocks/CU)
// ---------------------------------------------------------------------------
__global__ __launch_bounds__(256) void conv1_k(
    const unsigned short* __restrict__ XT, const unsigned short* __restrict__ wB,
    unsigned short* __restrict__ H1T)
{
    __shared__ __align__(16) unsigned short sA[3 * 66 * 68];   // 26928 B

    const int tid = threadIdx.x;
    const int x0  = blockIdx.x * 64;
    const int y   = blockIdx.y;
    const int sb  = blockIdx.z;
    const unsigned short* inT = XT + (size_t)sb * HWP * 64;

    stage_halo(sA, inT, x0, y, tid);
    __syncthreads();

    const int lane = tid & 63, wv = tid >> 6;
    const int mw = wv & 1, nw = wv >> 1;
    const int m = lane & 31, kg = lane >> 5;
    const int px_l = mw * 32 + m;

    float16 acc;
#pragma unroll
    for (int i = 0; i < 16; ++i) acc[i] = 0.f;

#pragma unroll
    for (int kc = 0; kc < 36; ++kc) {
        const int kd = kc >> 2, h = kc & 3;
        const int dy = kd / 3, dx = kd - dy * 3;
        bf16x8 af = *(const bf16x8*)&sA[((dy * 66 + px_l + dx) * 68) + h * 16 + kg * 8];
        bf16x8 bf = *(const bf16x8*)&wB[((kc * 2 + nw) * 64 + lane) * 8];
        acc = __builtin_amdgcn_mfma_f32_32x32x16_bf16(af, bf, acc, 0, 0, 0);
    }

    __syncthreads();
    unsigned short* sCb = sA;                 // [px][ci] stride 68
    const int n = nw * 32 + (lane & 31);
#pragma unroll
    for (int r = 0; r < 16; ++r) {
        int pr = mw * 32 + (r & 3) + 8 * (r >> 2) + 4 * kg;
        float v = acc[r];
        v = v > 0.f ? v : 0.1f * v;
        sCb[pr * 68 + n] = f2bf(v);
    }
    __syncthreads();

    const int px = tid >> 2, q = tid & 3;
    unsigned short* op = H1T + ((size_t)sb * HWP + y * WW + x0 + px) * 64;
#pragma unroll
    for (int r = 0; r < 2; ++r)
        *(uint4*)&op[(q * 2 + r) * 8] = *(uint4*)&sCb[px * 68 + (q * 2 + r) * 8];
}

// ---------------------------------------------------------------------------
// conv2 + residual + fused 1x1 projections (round-5 structure).
// side 0 (left):  buf tile -> Q proj -> QT bf16.
// side 1 (right): buf tile -> S,R proj -> ST, RT bf16.
// ---------------------------------------------------------------------------
__global__ __launch_bounds__(256) void conv2_k(
    const unsigned short* __restrict__ H1T, const unsigned short* __restrict__ XT,
    const unsigned short* __restrict__ wB2, const unsigned short* __restrict__ wQ,
    const unsigned short* __restrict__ wSR, const float* __restrict__ b1b,
    const float* __restrict__ b2b, const float* __restrict__ b3b,
    unsigned short* __restrict__ QT, unsigned short* __restrict__ ST,
    unsigned short* __restrict__ RT)
{
    __shared__ __align__(16) unsigned short sA[3 * 66 * 68];

    const int tid = threadIdx.x;
    const int x0  = blockIdx.x * 64;
    const int y   = blockIdx.y;
    const int sb  = blockIdx.z;
    const int side = sb >> 1, b = sb & 1;
    const unsigned short* inT = H1T + (size_t)sb * HWP * 64;

    stage_halo(sA, inT, x0, y, tid);
    __syncthreads();

    const int lane = tid & 63, wv = tid >> 6;
    const int mw = wv & 1, nw = wv >> 1;
    const int m = lane & 31, kg = lane >> 5;
    const int px_l = mw * 32 + m;

    float16 acc;
#pragma unroll
    for (int i = 0; i < 16; ++i) acc[i] = 0.f;

#pragma unroll
    for (int kc = 0; kc < 36; ++kc) {
        const int kd = kc >> 2, h = kc & 3;
        const int dy = kd / 3, dx = kd - dy * 3;
        bf16x8 af = *(const bf16x8*)&sA[((dy * 66 + px_l + dx) * 68) + h * 16 + kg * 8];
        bf16x8 bf = *(const bf16x8*)&wB2[((kc * 2 + nw) * 64 + lane) * 8];
        acc = __builtin_amdgcn_mfma_f32_32x32x16_bf16(af, bf, acc, 0, 0, 0);
    }

    // residual add (bf16 x from XT) -> buf tile bf16 in sCb [px][ci]
    __syncthreads();
    unsigned short* sCb = sA;                          // halves [0, 4352)
    unsigned short* sC2 = sA + 4352;                   // proj output staging
    const int n = nw * 32 + (lane & 31);
    const unsigned short* xres = XT + (size_t)sb * HWP * 64;
#pragma unroll
    for (int r = 0; r < 16; ++r) {
        int pr = mw * 32 + (r & 3) + 8 * (r >> 2) + 4 * kg;
        float xv = bf2f(xres[(size_t)(y * WW + x0 + pr) * 64 + n]);
        sCb[pr * 68 + n] = f2bf(acc[r] + xv);
    }
    __syncthreads();

    // fused projection MFMAs (K=64)
    if (side == 0) {
        float16 a2;
#pragma unroll
        for (int i = 0; i < 16; ++i) a2[i] = 0.f;
#pragma unroll
        for (int kc = 0; kc < 4; ++kc) {
            bf16x8 af = *(const bf16x8*)&sCb[px_l * 68 + kc * 16 + kg * 8];
            bf16x8 bf = *(const bf16x8*)&wQ[((kc * 2 + nw) * 64 + lane) * 8];
            a2 = __builtin_amdgcn_mfma_f32_32x32x16_bf16(af, bf, a2, 0, 0, 0);
        }
        float bv = b1b[n];
#pragma unroll
        for (int r = 0; r < 16; ++r) {
            int pr = mw * 32 + (r & 3) + 8 * (r >> 2) + 4 * kg;
            sC2[pr * 68 + n] = f2bf(a2[r] + bv);
        }
        __syncthreads();
        const int px = tid >> 2, q = tid & 3;
        unsigned short* op = QT + ((size_t)b * HWP + y * WW + x0 + px) * 64;
#pragma unroll
        for (int r = 0; r < 2; ++r)
            *(uint4*)&op[(q * 2 + r) * 8] = *(uint4*)&sC2[px * 68 + (q * 2 + r) * 8];
    } else {
        float16 a2[2];
#pragma unroll
        for (int t = 0; t < 2; ++t)
#pragma unroll
            for (int i = 0; i < 16; ++i) a2[t][i] = 0.f;
#pragma unroll
        for (int kc = 0; kc < 4; ++kc) {
            bf16x8 af = *(const bf16x8*)&sCb[px_l * 68 + kc * 16 + kg * 8];
#pragma unroll
            for (int t = 0; t < 2; ++t) {
                int nt = nw * 2 + t;
                bf16x8 bf = *(const bf16x8*)&wSR[((kc * 4 + nt) * 64 + lane) * 8];
                a2[t] = __builtin_amdgcn_mfma_f32_32x32x16_bf16(af, bf, a2[t], 0, 0, 0);
            }
        }
#pragma unroll
        for (int t = 0; t < 2; ++t) {
            int nn = (nw * 2 + t) * 32 + (lane & 31);
            float bv = (nn < 64) ? b2b[nn] : b3b[nn - 64];
#pragma unroll
            for (int r = 0; r < 16; ++r) {
                int pr = mw * 32 + (r & 3) + 8 * (r >> 2) + 4 * kg;
                sC2[pr * 132 + nn] = f2bf(a2[t][r] + bv);
            }
        }
        __syncthreads();
        const int px = tid >> 2, q = tid & 3;
        const size_t prow = (size_t)b * HWP + y * WW + x0 + px;
        unsigned short* op = ((q < 2) ? ST : RT) + prow * 64 + (q & 1) * 32;
#pragma unroll
        for (int j = 0; j < 4; ++j)
            *(uint4*)&op[j * 8] = *(uint4*)&sC2[px * 132 + q * 32 + j * 8];
    }
}

// ---------------------------------------------------------------------------
// Merged attention + fusion conv.  Block = 64 px, 512 thr (8 waves).
// Waves each process 8 px: score (lane=(cq,k), 2 shuffles), softmax over
// lane bits 0-3, V gather (lane=channel, readlane broadcast) -> bufT row in
// LDS.  Then waves 0-3 run the K=128 fuse MFMA (bufT from LDS, x_leftT
// staged) and write NCHW f32 out + bias.
// XCD swizzle: (blk&7)<4 -> batch 0, else batch 1 (halves per-XCD hot set).
// ---------------------------------------------------------------------------
__global__ __launch_bounds__(512) void attn_fuse_k(
    const unsigned short* __restrict__ QT, const unsigned short* __restrict__ ST,
    const unsigned short* __restrict__ RT, const int* __restrict__ xxs,
    const int* __restrict__ yys, const unsigned short* __restrict__ XT,
    const unsigned short* __restrict__ wfrag, const float* __restrict__ bias,
    float* __restrict__ out, float* __restrict__ Mout)
{
    __shared__ __align__(16) unsigned char smem[64 * 68 * 4];  // 17408 B
    unsigned short* sBuf = (unsigned short*)smem;            // [px][ch] str 68
    unsigned short* sXT  = (unsigned short*)smem + 64 * 68;  // [px][ch] str 68
    float*          sC   = (float*)smem;                     // [co][px] str 68

    const int tid  = threadIdx.x;
    const int lane = tid & 63;
    const int wv   = tid >> 6;

    const int blk = blockIdx.x;
    const int b   = (blk & 4) ? 1 : 0;
    const int sub = (blk >> 3) * 4 + (blk & 3);      // [0, 512)
    const int pofs = sub * 64;
    const size_t gp0   = (size_t)b * HWP + pofs;
    const size_t bbase = (size_t)b * HWP;

    // stage x_leftT rows (side 0)
    {
        const unsigned short* xlT = XT + gp0 * 64;
        int px = tid >> 3, j = tid & 7;
        *(uint4*)&sXT[px * 68 + j * 8] = *(const uint4*)&xlT[(size_t)px * 64 + j * 8];
    }

    // ---- attention: 8 px per wave ----
    const int k = lane & 15, cq = lane >> 4;
    for (int it = 0; it < 8; ++it) {
        const int pl = wv * 8 + it;
        const size_t gp = gp0 + pl;

        const int flat = xxs[gp * 16 + k] * WW + yys[gp * 16 + k];

        const unsigned short* srow = ST + (bbase + (size_t)flat) * 64 + cq * 16;
        const unsigned short* qrow = QT + gp * 64 + cq * 16;
        float s = 0.f;
#pragma unroll
        for (int hh = 0; hh < 2; ++hh) {
            uint4 sv = *(const uint4*)(srow + hh * 8);
            uint4 qv = *(const uint4*)(qrow + hh * 8);
            const unsigned* sa = (const unsigned*)&sv;
            const unsigned* qa = (const unsigned*)&qv;
#pragma unroll
            for (int d = 0; d < 4; ++d) {
                s = fmaf(__uint_as_float(sa[d] << 16),
                         __uint_as_float(qa[d] << 16), s);
                s = fmaf(__uint_as_float(sa[d] & 0xffff0000u),
                         __uint_as_float(qa[d] & 0xffff0000u), s);
            }
        }
        s += __shfl_xor(s, 16, 64);
        s += __shfl_xor(s, 32, 64);            // full score[k] on all lanes

        float mx = s;
#pragma unroll
        for (int mm = 1; mm <= 8; mm <<= 1) mx = fmaxf(mx, __shfl_xor(mx, mm, 64));
        const float e = __expf(s - mx);
        float sum = e;
#pragma unroll
        for (int mm = 1; mm <= 8; mm <<= 1) sum += __shfl_xor(sum, mm, 64);
        const float mval = e * (1.f / sum);

        if (lane < 16) Mout[gp * 16 + lane] = mval;

        const unsigned short* rbase = RT + bbase * 64;
        float acc = 0.f;
#pragma unroll
        for (int kk = 0; kk < 16; ++kk) {
            int   fi = __builtin_amdgcn_readlane(flat, kk);
            float mk = __uint_as_float(
                __builtin_amdgcn_readlane(__float_as_uint(mval), kk));
            acc = fmaf(mk, bf2f(rbase[(size_t)fi * 64 + lane]), acc);
        }
        sBuf[pl * 68 + lane] = f2bf(acc);
    }
    __syncthreads();

    // ---- fuse MFMA on waves 0-3 ----
    float16 facc;
#pragma unroll
    for (int i = 0; i < 16; ++i) facc[i] = 0.f;
    const int mw = wv & 1, nw = (wv >> 1) & 1;
    const int m = lane & 31, kg = lane >> 5;
    const int px_l = mw * 32 + m;

    if (tid < 256) {
#pragma unroll
        for (int kc = 0; kc < 8; ++kc) {
            const unsigned short* asrc = (kc < 4)
                ? &sBuf[px_l * 68 + kc * 16 + kg * 8]
                : &sXT[px_l * 68 + (kc - 4) * 16 + kg * 8];
            bf16x8 af = *(const bf16x8*)asrc;
            bf16x8 bf = *(const bf16x8*)&wfrag[((kc * 2 + nw) * 64 + lane) * 8];
            facc = __builtin_amdgcn_mfma_f32_32x32x16_bf16(af, bf, facc, 0, 0, 0);
        }
    }
    __syncthreads();   // all MFMA reads of sBuf/sXT done before sC overwrite

    if (tid < 256) {
        const int co_l = nw * 32 + (lane & 31);
#pragma unroll
        for (int r = 0; r < 16; ++r) {
            int pr = mw * 32 + (r & 3) + 8 * (r >> 2) + 4 * kg;
            sC[co_l * 68 + pr] = facc[r];
        }
    }
    __syncthreads();

    if (tid < 256) {
        const int co = tid >> 2, p0 = (tid & 3) * 16;
        const float bv = bias[co];
        float* op = out + ((size_t)b * CH + co) * HWP + pofs + p0;
#pragma unroll
        for (int q = 0; q < 4; ++q) {
            float4 v = *(float4*)&sC[co * 68 + p0 + q * 4];
            v.x += bv; v.y += bv; v.z += bv; v.w += bv;
            *(float4*)&op[q * 4] = v;
        }
    }
}

// ---------------------------------------------------------------------------
extern "C" void kernel_launch(void* const* d_in, const int* in_sizes, int n_in,
                              void* d_out, int out_size, void* d_ws, size_t ws_size,
                              hipStream_t stream)
{
    const float* x_left  = (const float*)d_in[0];
    const float* x_right = (const float*)d_in[1];
    const int*   xxs     = (const int*)d_in[2];
    const int*   yys     = (const int*)d_in[3];
    const float* rb_w1   = (const float*)d_in[5];
    const float* rb_w2   = (const float*)d_in[6];
    const float* b1_w    = (const float*)d_in[7];
    const float* b1_b    = (const float*)d_in[8];
    const float* b2_w    = (const float*)d_in[9];
    const float* b2_b    = (const float*)d_in[10];
    const float* b3_w    = (const float*)d_in[11];
    const float* b3_b    = (const float*)d_in[12];
    const float* fus_w   = (const float*)d_in[13];
    const float* fus_b   = (const float*)d_in[14];

    float* out  = (float*)d_out;                 // (2,64,128,256)
    float* Mout = out + (size_t)2 * CH * HWP;    // (2,32768,1,16)

    unsigned short* ws2 = (unsigned short*)d_ws;
    unsigned short* XT   = ws2;                  // [side][b][HWP][64]  8388608
    unsigned short* H1T  = ws2 + 8388608;
    unsigned short* QT   = ws2 + 16777216;       // [b][HWP][64]        4194304
    unsigned short* ST   = ws2 + 20971520;
    unsigned short* RT   = ws2 + 25165824;
    unsigned short* wB   = ws2 + 29360128;       // 94208 halves

    prep_w_k<<<368, 256, 0, stream>>>(rb_w1, rb_w2, b1_w, b2_w, b3_w, fus_w, wB);
    toT_k<<<2048, 256, 0, stream>>>(x_left, x_right, XT);

    dim3 cgrid(WW / 64, HH, 4), cblk(256);
    conv1_k<<<cgrid, cblk, 0, stream>>>(XT, wB, H1T);
    conv2_k<<<cgrid, cblk, 0, stream>>>(H1T, XT, wB + 36864, wB + 73728,
                                        wB + 77824, b1_b, b2_b, b3_b, QT, ST, RT);

    attn_fuse_k<<<1024, 512, 0, stream>>>(QT, ST, RT, xxs, yys, XT,
                                          wB + 86016, fus_b, out, Mout);
}